// Round 14
// baseline (251.658 us; speedup 1.0000x reference)
//
#include <hip/hip_runtime.h>

#define HW 512
#define NPIX (HW * HW)        // 262144 pixels
#define LDS_PIX 163840        // 160 KB u8 slice in LDS (62.5% of table)
#define THREADS 1024          // 16 waves/block, 1 block/CU (LDS-capped)
#define BLOCKS 512            // 2 sequential blocks/CU — R5-proven best
#define RNDS 8                // 8 pair-rounds = 16 elems/thread; 524288*16 = N

// Reference constants
#define EPS_F  1e-10f
constexpr double B_d  = 1.0 + 0.1 + 0.05;        // 1.15
constexpr double BR_d = 1.0 + 0.1 - 0.05;        // 1.05
#define B_F    ((float)B_d)
#define INVB_F ((float)(1.0 / B_d))
#define BR_F   ((float)BR_d)
#define BL_F   ((float)(1.0 / BR_d))

typedef __attribute__((ext_vector_type(4))) int   ivec4;
typedef __attribute__((ext_vector_type(2))) int   ivec2;
typedef __attribute__((ext_vector_type(2))) float fvec2;

// u8 table: k = round(m*255), v = (k+1)/256. |dv| <= 1/512; measured final
// absmax 1.95e-3 vs threshold 7.07e-3.
__global__ void build_v(const float* __restrict__ vin,
                        unsigned char* __restrict__ vq,
                        float* __restrict__ out) {
    int i = blockIdx.x * blockDim.x + threadIdx.x;
    if (i == 0) *out = 0.0f;                     // fold d_out zero-init here
    if (i < NPIX) {
        float s = vin[i] + vin[i + NPIX] + vin[i + 2 * NPIX];
        float m = s * (1.0f / 3.0f);
        vq[i] = (unsigned char)__float2int_rn(m * 255.0f);
    }
}

__device__ __forceinline__ float rcp_fast(float x) {
#if __has_builtin(__builtin_amdgcn_rcpf)
    return __builtin_amdgcn_rcpf(x);             // v_rcp_f32, ~1 ulp — margin is 3.6x
#else
    return 1.0f / x;
#endif
}

__device__ __forceinline__ float per_loss(float r1, float r2, int d) {
    float ratio = r1 * rcp_fast(r2 + EPS_F);
    float rinv  = r2 * rcp_fast(r1 + EPS_F);
    float l1 = (ratio > INVB_F) ? (ratio - INVB_F + (B_F - rinv)) : 0.0f;
    float l2 = (ratio < B_F)    ? (B_F - ratio + (rinv - INVB_F)) : 0.0f;
    float l0 = (ratio > BR_F)   ? (ratio - BR_F + (BL_F - rinv))
             : ((ratio < BL_F)  ? (BL_F - ratio + (rinv - BR_F)) : 0.0f);
    return (d == 1) ? l1 : ((d == 2) ? l2 : l0);
}

// ---- pair-vectorized pipeline building blocks.  Pair p = elements 2p,2p+1
// (p = tid + round*T): coords 32B contiguous/thread, darker int2, weights
// float2 — stream instrs/round 6 -> 4, d/w bytes per queue slot doubled. ----

__device__ __forceinline__ void load_c(ivec4 (&cc)[2], const ivec4* __restrict__ coords,
                                       int pp) {
    cc[0] = __builtin_nontemporal_load(&coords[2 * pp]);
    cc[1] = __builtin_nontemporal_load(&coords[2 * pp + 1]);
}

__device__ __forceinline__ void load_dw(ivec2& dd, fvec2& ww,
                                        const int* __restrict__ darker,
                                        const float* __restrict__ weights,
                                        int pp) {
    dd = __builtin_nontemporal_load((const ivec2*)&darker[2 * pp]);
    ww = __builtin_nontemporal_load((const fvec2*)&weights[2 * pp]);
}

// Hybrid gather: 62.5% of lanes hit LDS, rest go global (table L2/L3-resident;
// NT streams don't evict it).
__device__ __forceinline__ void gather_issue(const ivec4 (&cc)[2],
        unsigned (&q1)[2], unsigned (&q2)[2],
        const unsigned char* lv, const unsigned char* __restrict__ vq) {
    #pragma unroll
    for (int k = 0; k < 2; ++k) {
        int i1 = cc[k].y * HW + cc[k].x;
        int i2 = cc[k].w * HW + cc[k].z;
        if (i1 < LDS_PIX) q1[k] = lv[i1]; else q1[k] = vq[i1];
        if (i2 < LDS_PIX) q2[k] = lv[i2]; else q2[k] = vq[i2];
    }
}

__device__ __forceinline__ void consume(const unsigned (&q1)[2], const unsigned (&q2)[2],
                                        const ivec2& dd, const fvec2& ww,
                                        float& acc) {
    #pragma unroll
    for (int k = 0; k < 2; ++k) {
        float r1 = (float)(q1[k] + 1) * (1.0f / 256.0f);
        float r2 = (float)(q2[k] + 1) * (1.0f / 256.0f);
        acc += ww[k] * per_loss(r1, r2, dd[k]);
    }
}

#define SBAR() __builtin_amdgcn_sched_barrier(0)

// Champion structure (R5): 1024-thr blocks (natural 64-VGPR budget), state
// sized under it (~47 live regs), 160 KB LDS, gathers 1 round ahead,
// streams 2 ahead.  WRITE_SIZE ~39 MB seen on this config is L3 writeback
// of the harness poison fill, not scratch (R10 vs R11: NB-independent).
__global__ __launch_bounds__(THREADS)
void whdr_kernel(
        const unsigned char* __restrict__ vq,
        const ivec4* __restrict__ coords,
        const int*   __restrict__ darker,
        const float* __restrict__ weights,
        float*       __restrict__ out,
        int n) {
    __shared__ unsigned char lv[LDS_PIX];        // 160 KB -> 1 block/CU
    const int tid = blockIdx.x * THREADS + threadIdx.x;
    const int T   = BLOCKS * THREADS;            // 524288 threads = pair stride
    float acc = 0.0f;

    if (n == T * 2 * RNDS) {
        // ---- steady-state: 8 pair-rounds; streams A/B ping-pong 2 rounds
        // ahead, gathers double-buffered 1 round ahead ----
        ivec4 cA[2], cB[2];
        ivec2 dA, dB;
        fvec2 wA, wB;
        unsigned qA1[2], qA2[2], qB1[2], qB2[2];

        load_c (cA, coords, tid + 0 * T);
        load_dw(dA, wA, darker, weights, tid + 0 * T);
        load_c (cB, coords, tid + 1 * T);
        load_dw(dB, wB, darker, weights, tid + 1 * T);
        {   // cooperative LDS fill: 160 B/thread, 16B coalesced
            const uint4* s4 = (const uint4*)vq;
            uint4* d4 = (uint4*)lv;
            #pragma unroll
            for (int j = threadIdx.x; j < LDS_PIX / 16; j += THREADS) d4[j] = s4[j];
        }
        __syncthreads();
        gather_issue(cA, qA1, qA2, lv, vq);            SBAR();  // G0

#define RPF(r, CUR, NXT) \
        gather_issue(c##NXT, q##NXT##1, q##NXT##2, lv, vq);        SBAR(); \
        load_c (c##CUR, coords, tid + (r + 2) * T);                SBAR(); \
        consume(q##CUR##1, q##CUR##2, d##CUR, w##CUR, acc); \
        load_dw(d##CUR, w##CUR, darker, weights, tid + (r + 2) * T); SBAR();

        RPF(0, A, B)
        RPF(1, B, A)
        RPF(2, A, B)
        RPF(3, B, A)
        RPF(4, A, B)
        RPF(5, B, A)
#undef RPF
        // round 6: gather r7(B), consume r6(A) — no more stream prefetch
        gather_issue(cB, qB1, qB2, lv, vq);            SBAR();
        consume(qA1, qA2, dA, wA, acc);
        // round 7: drain
        consume(qB1, qB2, dB, wB, acc);
    } else {
        // ---- generic fallback (any n) ----
        {
            const uint4* s4 = (const uint4*)vq;
            uint4* d4 = (uint4*)lv;
            for (int j = threadIdx.x; j < LDS_PIX / 16; j += THREADS) d4[j] = s4[j];
        }
        __syncthreads();
        const int TT = gridDim.x * THREADS;
        for (int i = tid; i < n; i += TT) {
            ivec4 c = coords[i];
            int i1 = c.y * HW + c.x, i2 = c.w * HW + c.z;
            unsigned a = (i1 < LDS_PIX) ? (unsigned)lv[i1] : (unsigned)vq[i1];
            unsigned b = (i2 < LDS_PIX) ? (unsigned)lv[i2] : (unsigned)vq[i2];
            float r1 = (float)(a + 1) * (1.0f / 256.0f);
            float r2 = (float)(b + 1) * (1.0f / 256.0f);
            acc += weights[i] * per_loss(r1, r2, darker[i]);
        }
    }

    // wave-64 shuffle reduction
    #pragma unroll
    for (int off = 32; off > 0; off >>= 1)
        acc += __shfl_down(acc, off, 64);
    // Reuse lv's LDS for the block reduction (table reads done; barrier
    // orders the reuse).
    __syncthreads();
    float* wsum = (float*)lv;
    int lane = threadIdx.x & 63;
    int wid  = threadIdx.x >> 6;                 // 16 waves
    if (lane == 0) wsum[wid] = acc;
    __syncthreads();
    if (threadIdx.x == 0) {
        float s = 0.0f;
        #pragma unroll
        for (int i = 0; i < THREADS / 64; ++i) s += wsum[i];
        atomicAdd(out, s / (float)n);            // n = 2^23 -> exact
    }
}

extern "C" void kernel_launch(void* const* d_in, const int* in_sizes, int n_in,
                              void* d_out, int out_size, void* d_ws, size_t ws_size,
                              hipStream_t stream) {
    const float* v_input = (const float*)d_in[0];  // (3,512,512) f32
    const ivec4* coords  = (const ivec4*)d_in[1];  // (N,4) i32
    const int*   darker  = (const int*)d_in[2];    // (N,) i32
    const float* weights = (const float*)d_in[3];  // (N,) f32
    float* out = (float*)d_out;
    unsigned char* vq = (unsigned char*)d_ws;      // 256 KB u8 v table
    int n = in_sizes[2];                           // N

    build_v<<<(NPIX + 255) / 256, 256, 0, stream>>>(v_input, vq, out);
    whdr_kernel<<<BLOCKS, THREADS, 0, stream>>>(vq, coords, darker, weights, out, n);
}